// Round 6
// baseline (235.687 us; speedup 1.0000x reference)
//
#include <hip/hip_runtime.h>

// KDE entropy loss, MI355X/gfx950 — fp8 fused GEMM, symmetric pairs once,
// wrapped-diagonal mapping, A-in-registers, single 32KB B buffer ->
// 4 blocks/CU (4 waves/SIMD TLP), ticketed in-kernel final reduction.
// ws: [0,4MiB) Xn fp8 [16384][256]; [4MiB,+64KiB) density f32; then ticket u32.

#define NROWS 16384
#define KDIM 256            // bytes per fp8 row
#define NTILE 128
#define NT (NROWS / NTILE)  // 128 tile rows
#define NSTRIP 8
#define TOTAL_BLOCKS (NT * NSTRIP)  // 1024 = exactly 4 per CU

// sqrt(5 * log2(e)): folded into both operands -> sim scaled by 5*log2(e),
// so kernel = exp2(sim_scaled) = exp(5*sim).
#define SQRT_KLOG2E 2.68579577857f

typedef int i32x4_t __attribute__((ext_vector_type(4)));
typedef int i32x8_t __attribute__((ext_vector_type(8)));
typedef float f32x16_t __attribute__((ext_vector_type(16)));
typedef __attribute__((address_space(1))) const void global_cvoid_t;
typedef __attribute__((address_space(3))) void lds_void_t;

#if __has_builtin(__builtin_amdgcn_exp2f)
#define EXP2(x) __builtin_amdgcn_exp2f(x)
#else
#define EXP2(x) exp2f(x)
#endif

union frag8 { i32x8_t v8; i32x4_t v4[2]; };

// One wave per row: sqrt(5log2e)/max(||x||,eps), fp8 e4m3 out; zero density+ticket.
__global__ __launch_bounds__(256)
void kde_normalize(const float* __restrict__ X, unsigned int* __restrict__ Xn8,
                   float* __restrict__ density, unsigned int* __restrict__ ticket) {
  const int wave = threadIdx.x >> 6;
  const int lane = threadIdx.x & 63;
  const int row = blockIdx.x * 4 + wave;
  const float4 v = ((const float4*)(X + (size_t)row * KDIM))[lane];
  float ss = v.x * v.x + v.y * v.y + v.z * v.z + v.w * v.w;
  ss += __shfl_xor(ss, 1);
  ss += __shfl_xor(ss, 2);
  ss += __shfl_xor(ss, 4);
  ss += __shfl_xor(ss, 8);
  ss += __shfl_xor(ss, 16);
  ss += __shfl_xor(ss, 32);
  const float scale = SQRT_KLOG2E / fmaxf(sqrtf(ss), 1e-12f);
  int p = 0;
  p = __builtin_amdgcn_cvt_pk_fp8_f32(v.x * scale, v.y * scale, p, false);
  p = __builtin_amdgcn_cvt_pk_fp8_f32(v.z * scale, v.w * scale, p, true);
  Xn8[(size_t)row * 64 + lane] = (unsigned int)p;
  if (threadIdx.x < 4) density[blockIdx.x * 4 + threadIdx.x] = 0.0f;
  if (blockIdx.x == 0 && threadIdx.x == 0) *ticket = 0u;
}

// Block (bi, s): row tile bi; J = (bi+t) mod 128 for t in [s*8, s*8+8)
// (+ t=64 for s==0, bi<64 — those blocks dispatch FIRST, so the 9-iter tail
// starts earliest). Each unordered tile pair once. 4 waves 2x2 over 128x128;
// wave = 2x2 MFMA 32x32x64 fp8 (scale=1 -> exact e4m3). A in registers;
// B in a single 32 KB LDS buffer -> 4 blocks/CU: stalls of one block are
// covered by the other three (TLP, m114-style overlap).
__global__ __launch_bounds__(256, 4)
void kde_gemm(const unsigned char* __restrict__ Xn8, float* __restrict__ density,
              unsigned int* __restrict__ ticket, float* __restrict__ out) {
  extern __shared__ char smem[];
  char* buf = smem;  // 32 KB

  const int tid = threadIdx.x;
  const int wave = tid >> 6;
  const int lane = tid & 63;
  const int wr = wave >> 1;
  const int wc = wave & 1;
  const int m32 = lane & 31;
  const int h = lane >> 5;
  const int bi = blockIdx.x;
  const int s = blockIdx.y;
  const int nt = (s == 0 && bi < NT / 2) ? 9 : 8;
  const char* Xb = (const char*)Xn8;

  // Chunk c = rt*8 + kb*2 + hh: lane holds M[rt*32+m32][kb*64+h*32+hh*16 ..+15].
#define STAGE(base_row)                                                           \
  for (int c = wave; c < 32; c += 4) {                                            \
    const int rt = c >> 3, kb = (c >> 1) & 3, hh = c & 1;                         \
    const size_t gofs =                                                           \
        (size_t)((base_row) + rt * 32 + m32) * KDIM + kb * 64 + h * 32 + hh * 16; \
    __builtin_amdgcn_global_load_lds((global_cvoid_t*)(Xb + gofs),                \
                                     (lds_void_t*)(buf + c * 1024), 16, 0, 0);    \
  }

  // A tile through the buffer into registers (reused across all nt J-tiles).
  STAGE(bi * NTILE);
  __syncthreads();  // A landed
  frag8 areg[2][4];
#pragma unroll
  for (int i = 0; i < 2; i++)
#pragma unroll
    for (int kb = 0; kb < 4; kb++) {
      const char* pa = buf + ((wr * 2 + i) * 8 + kb * 2) * 1024 + lane * 16;
      areg[i][kb].v4[0] = *(const i32x4_t*)pa;
      areg[i][kb].v4[1] = *(const i32x4_t*)(pa + 1024);
    }
  __syncthreads();  // all waves done reading A from buf

  float rs[2][16];
#pragma unroll
  for (int i = 0; i < 2; i++)
#pragma unroll
    for (int r = 0; r < 16; r++) rs[i][r] = 0.0f;

  for (int k = 0; k < nt; ++k) {
    const int t = (k == 8) ? 64 : s * 8 + k;
    const int J = (bi + t) & (NT - 1);

    STAGE(J * NTILE);
    __syncthreads();  // B(k) landed (vmcnt drained; prev-iter atomics too)

    f32x16_t acc[2][2];
#pragma unroll
    for (int i = 0; i < 2; i++)
#pragma unroll
      for (int j = 0; j < 2; j++) acc[i][j] = (f32x16_t)0.0f;

#pragma unroll
    for (int kb = 0; kb < 4; ++kb) {
      frag8 bf[2];
#pragma unroll
      for (int j = 0; j < 2; j++) {
        const char* pb = buf + ((wc * 2 + j) * 8 + kb * 2) * 1024 + lane * 16;
        bf[j].v4[0] = *(const i32x4_t*)pb;
        bf[j].v4[1] = *(const i32x4_t*)(pb + 1024);
      }
#pragma unroll
      for (int i = 0; i < 2; i++)
#pragma unroll
        for (int j = 0; j < 2; j++)
          acc[i][j] = __builtin_amdgcn_mfma_scale_f32_32x32x64_f8f6f4(
              areg[i][kb].v8, bf[j].v8, acc[i][j], 0, 0, 0, 127, 0, 127);
    }

    // Epilogue: e = exp2(sim_scaled) = exp(5*sim). rowsums in regs across k,
    // colsums scattered now. C/D: col = m32, row = (r&3) + 8*(r>>2) + 4*h.
    float cs[2] = {0.0f, 0.0f};
#pragma unroll
    for (int i = 0; i < 2; i++)
#pragma unroll
      for (int j = 0; j < 2; j++)
#pragma unroll
        for (int r = 0; r < 16; r++) {
          const float e = EXP2(acc[i][j][r]);
          rs[i][r] += e;
          cs[j] += e;
        }

    if (t != 0) {  // diagonal tile (t=0): rowsum only
#pragma unroll
      for (int j = 0; j < 2; j++) {
        float v = cs[j] + __shfl_xor(cs[j], 32);  // combine h halves -> 64 rows
        if (h == 0)  // 2 atomics/col (wr=0,1 waves)
          atomicAdd(&density[J * NTILE + wc * 64 + j * 32 + m32], v);
      }
    }

    __syncthreads();  // all waves done reading buf; safe to restage
  }

  // Row epilogue: reduce over 32 cols (m32) then scatter; 2 atomics/row (wc).
#pragma unroll
  for (int i = 0; i < 2; i++)
#pragma unroll
    for (int r = 0; r < 16; r++) {
      float v = rs[i][r];
      v += __shfl_xor(v, 1);
      v += __shfl_xor(v, 2);
      v += __shfl_xor(v, 4);
      v += __shfl_xor(v, 8);
      v += __shfl_xor(v, 16);
      if (m32 == 0) {
        const int row = bi * NTILE + wr * 64 + i * 32 + (r & 3) + 8 * (r >> 2) + 4 * h;
        atomicAdd(&density[row], v);
      }
    }
#undef STAGE

  // Ticket: last finished block computes the entropy (saves 2 launches).
  __syncthreads();  // all waves' atomics issued & drained (vmcnt(0) at barrier)
  if (tid == 0) {
    __threadfence();
    ((volatile unsigned int*)smem)[0] = atomicAdd(ticket, 1u);
  }
  __syncthreads();
  if (((volatile unsigned int*)smem)[0] == TOTAL_BLOCKS - 1) {
    __threadfence();
    float ssum = 0.0f;
    for (int i = tid; i < NROWS; i += 256) {
      const float d = __hip_atomic_load(&density[i], __ATOMIC_RELAXED,
                                        __HIP_MEMORY_SCOPE_AGENT);
      ssum += logf(d + 1e-9f);
    }
    ssum += __shfl_xor(ssum, 1);
    ssum += __shfl_xor(ssum, 2);
    ssum += __shfl_xor(ssum, 4);
    ssum += __shfl_xor(ssum, 8);
    ssum += __shfl_xor(ssum, 16);
    ssum += __shfl_xor(ssum, 32);
    float* red = ((float*)smem) + 16;
    if (lane == 0) red[wave] = ssum;
    __syncthreads();
    if (tid == 0) out[0] = -(red[0] + red[1] + red[2] + red[3]) / (float)NROWS;
  }
}

extern "C" void kernel_launch(void* const* d_in, const int* in_sizes, int n_in,
                              void* d_out, int out_size, void* d_ws, size_t ws_size,
                              hipStream_t stream) {
  const float* X = (const float*)d_in[0];
  float* out = (float*)d_out;
  char* ws = (char*)d_ws;
  unsigned int* Xn8 = (unsigned int*)ws;
  float* density = (float*)(ws + (size_t)NROWS * KDIM);
  unsigned int* ticket = (unsigned int*)(density + NROWS);

  hipFuncSetAttribute((const void*)kde_gemm,
                      hipFuncAttributeMaxDynamicSharedMemorySize, 32768);

  kde_normalize<<<NROWS / 4, 256, 0, stream>>>(X, Xn8, density, ticket);
  kde_gemm<<<dim3(NT, NSTRIP), 256, 32768, stream>>>((const unsigned char*)ws,
                                                     density, ticket, out);
}

// Round 7
// 124.494 us; speedup vs baseline: 1.8932x; 1.8932x over previous
//
#include <hip/hip_runtime.h>

// KDE entropy loss, MI355X/gfx950 — fp8 fused GEMM, symmetric pairs once,
// wrapped-diagonal mapping. 512-thread blocks (8 waves, 4x2 over 128x128,
// wave tile 32x64) -> per-wave regs fit 128 cap -> 4 waves/SIMD at
// 2 blocks/CU without spilling (R6's launch_bounds(256,4) spilled: 344MB
// FETCH of scratch traffic). A-in-registers, double-buffered B, 1 barrier
// per J-tile, ticketed in-kernel final reduction.
// ws: [0,4MiB) Xn fp8 [16384][256]; [4MiB,+64KiB) density f32; then ticket u32.

#define NROWS 16384
#define KDIM 256            // bytes per fp8 row
#define NTILE 128
#define NT (NROWS / NTILE)  // 128 tile rows
#define NSTRIP 4
#define TOTAL_BLOCKS (NT * NSTRIP)  // 512 blocks of 512 thr = exactly 2 per CU

// sqrt(5 * log2(e)): folded into both operands -> sim scaled by 5*log2(e),
// so kernel = exp2(sim_scaled) = exp(5*sim).
#define SQRT_KLOG2E 2.68579577857f

typedef int i32x4_t __attribute__((ext_vector_type(4)));
typedef int i32x8_t __attribute__((ext_vector_type(8)));
typedef float f32x16_t __attribute__((ext_vector_type(16)));
typedef __attribute__((address_space(1))) const void global_cvoid_t;
typedef __attribute__((address_space(3))) void lds_void_t;

#if __has_builtin(__builtin_amdgcn_exp2f)
#define EXP2(x) __builtin_amdgcn_exp2f(x)
#else
#define EXP2(x) exp2f(x)
#endif

union frag8 { i32x8_t v8; i32x4_t v4[2]; };

// One wave per row: sqrt(5log2e)/max(||x||,eps), fp8 e4m3 out; zero density+ticket.
__global__ __launch_bounds__(256)
void kde_normalize(const float* __restrict__ X, unsigned int* __restrict__ Xn8,
                   float* __restrict__ density, unsigned int* __restrict__ ticket) {
  const int wave = threadIdx.x >> 6;
  const int lane = threadIdx.x & 63;
  const int row = blockIdx.x * 4 + wave;
  const float4 v = ((const float4*)(X + (size_t)row * KDIM))[lane];
  float ss = v.x * v.x + v.y * v.y + v.z * v.z + v.w * v.w;
  ss += __shfl_xor(ss, 1);
  ss += __shfl_xor(ss, 2);
  ss += __shfl_xor(ss, 4);
  ss += __shfl_xor(ss, 8);
  ss += __shfl_xor(ss, 16);
  ss += __shfl_xor(ss, 32);
  const float scale = SQRT_KLOG2E / fmaxf(sqrtf(ss), 1e-12f);
  int p = 0;
  p = __builtin_amdgcn_cvt_pk_fp8_f32(v.x * scale, v.y * scale, p, false);
  p = __builtin_amdgcn_cvt_pk_fp8_f32(v.z * scale, v.w * scale, p, true);
  Xn8[(size_t)row * 64 + lane] = (unsigned int)p;
  if (threadIdx.x < 4) density[blockIdx.x * 4 + threadIdx.x] = 0.0f;
  if (blockIdx.x == 0 && threadIdx.x == 0) *ticket = 0u;
}

// Block (bi, s): row tile bi; J = (bi+t) mod 128 for t in [s*16, s*16+16)
// (+ t=64 for s==0, bi<64 — dispatched first so the 17-iter blocks start
// earliest). Each unordered tile pair once. 8 waves 4x2 over 128x128; wave =
// 32x64 = 1x2 MFMA 32x32x64 fp8 (scale=1 -> exact e4m3). A in registers
// (32 VGPR); B double-buffers in 64 KB LDS; 1 barrier/iter.
__global__ __launch_bounds__(512, 4)
void kde_gemm(const unsigned char* __restrict__ Xn8, float* __restrict__ density,
              unsigned int* __restrict__ ticket, float* __restrict__ out) {
  extern __shared__ char smem[];
  char* buf0 = smem;           // 32 KB
  char* buf1 = smem + 32768;   // 32 KB

  const int tid = threadIdx.x;
  const int wave = tid >> 6;   // 0..7
  const int lane = tid & 63;
  const int wr = wave >> 1;    // row quarter 0..3 (32 rows each)
  const int wc = wave & 1;     // col half 0..1 (64 cols each)
  const int m32 = lane & 31;
  const int h = lane >> 5;
  const int bi = blockIdx.x;
  const int s = blockIdx.y;
  const int t0 = s * 16;
  const int nt = (s == 0 && bi < NT / 2) ? 17 : 16;
  const char* Xb = (const char*)Xn8;

  // Chunk c = rt*8 + kb*2 + hh: lane holds M[rt*32+m32][kb*64+h*32+hh*16 ..+15]
  // (identical layout to R5's verified kernel; 4 chunks per wave now).
#define STAGE(base_row, dst)                                                      \
  for (int c = wave; c < 32; c += 8) {                                            \
    const int rt = c >> 3, kb = (c >> 1) & 3, hh = c & 1;                         \
    const size_t gofs =                                                           \
        (size_t)((base_row) + rt * 32 + m32) * KDIM + kb * 64 + h * 32 + hh * 16; \
    __builtin_amdgcn_global_load_lds((global_cvoid_t*)(Xb + gofs),                \
                                     (lds_void_t*)((dst) + c * 1024), 16, 0, 0);  \
  }

  STAGE(bi * NTILE, buf0);                      // A tile -> buf0
  STAGE(((bi + t0) & (NT - 1)) * NTILE, buf1);  // B(0)   -> buf1
  __syncthreads();  // both landed (vmcnt drained at barrier)

  // A fragments -> registers: this wave's 32 rows, full K (32 VGPRs).
  frag8 areg[4];
#pragma unroll
  for (int kb = 0; kb < 4; kb++) {
    const char* pa = buf0 + (wr * 8 + kb * 2) * 1024 + lane * 16;
    areg[kb].v4[0] = *(const i32x4_t*)pa;
    areg[kb].v4[1] = *(const i32x4_t*)(pa + 1024);
  }
  __syncthreads();  // all waves done reading A from buf0

  float rs[16];
#pragma unroll
  for (int r = 0; r < 16; r++) rs[r] = 0.0f;

  for (int k = 0; k < nt; ++k) {
    const int t = t0 + (k == 16 ? 48 : k) + (k == 16 ? 16 : 0);  // t0+k; k==16 -> 64
    const int J = (bi + t) & (NT - 1);
    char* rbuf = (k & 1) ? buf0 : buf1;  // B(k): landed at last barrier
    char* sbuf = (k & 1) ? buf1 : buf0;  // free since last barrier

    if (k + 1 < nt) {
      const int tn = t0 + (k + 1 == 16 ? 64 : k + 1);
      STAGE(((bi + tn) & (NT - 1)) * NTILE, sbuf);
    }

    f32x16_t acc[2];
#pragma unroll
    for (int j = 0; j < 2; j++) acc[j] = (f32x16_t)0.0f;

#pragma unroll
    for (int kb = 0; kb < 4; ++kb) {
      frag8 bf[2];
#pragma unroll
      for (int j = 0; j < 2; j++) {
        const char* pb = rbuf + ((wc * 2 + j) * 8 + kb * 2) * 1024 + lane * 16;
        bf[j].v4[0] = *(const i32x4_t*)pb;
        bf[j].v4[1] = *(const i32x4_t*)(pb + 1024);
      }
#pragma unroll
      for (int j = 0; j < 2; j++)
        acc[j] = __builtin_amdgcn_mfma_scale_f32_32x32x64_f8f6f4(
            areg[kb].v8, bf[j].v8, acc[j], 0, 0, 0, 127, 0, 127);
    }

    // Epilogue: e = exp2(sim_scaled) = exp(5*sim). rowsums in regs across k,
    // colsums scattered now. C/D: col = m32, row = (r&3) + 8*(r>>2) + 4*h.
    float cs[2] = {0.0f, 0.0f};
#pragma unroll
    for (int j = 0; j < 2; j++)
#pragma unroll
      for (int r = 0; r < 16; r++) {
        const float e = EXP2(acc[j][r]);
        rs[r] += e;
        cs[j] += e;
      }

    if (t != 0) {  // diagonal tile (t=0): rowsum only
#pragma unroll
      for (int j = 0; j < 2; j++) {
        float v = cs[j] + __shfl_xor(cs[j], 32);  // combine h halves -> 32 rows
        if (h == 0)  // 4 atomics/col (wr=0..3 waves)
          atomicAdd(&density[J * NTILE + wc * 64 + j * 32 + m32], v);
      }
    }

    __syncthreads();  // B(k+1) landed; all waves done reading rbuf
  }

  // Row epilogue: reduce over 32 cols (m32), scatter; 2 atomics/row (wc=0,1).
#pragma unroll
  for (int r = 0; r < 16; r++) {
    float v = rs[r];
    v += __shfl_xor(v, 1);
    v += __shfl_xor(v, 2);
    v += __shfl_xor(v, 4);
    v += __shfl_xor(v, 8);
    v += __shfl_xor(v, 16);
    if (m32 == 0) {
      const int row = bi * NTILE + wr * 32 + (r & 3) + 8 * (r >> 2) + 4 * h;
      atomicAdd(&density[row], v);
    }
  }
#undef STAGE

  // Ticket: last finished block computes the entropy (saves 2 launches).
  __syncthreads();  // all waves' atomics issued & drained (vmcnt(0) at barrier)
  if (tid == 0) {
    __threadfence();
    ((volatile unsigned int*)smem)[0] = atomicAdd(ticket, 1u);
  }
  __syncthreads();
  if (((volatile unsigned int*)smem)[0] == TOTAL_BLOCKS - 1) {
    __threadfence();
    float ssum = 0.0f;
    for (int i = tid; i < NROWS; i += 512) {
      const float d = __hip_atomic_load(&density[i], __ATOMIC_RELAXED,
                                        __HIP_MEMORY_SCOPE_AGENT);
      ssum += logf(d + 1e-9f);
    }
    ssum += __shfl_xor(ssum, 1);
    ssum += __shfl_xor(ssum, 2);
    ssum += __shfl_xor(ssum, 4);
    ssum += __shfl_xor(ssum, 8);
    ssum += __shfl_xor(ssum, 16);
    ssum += __shfl_xor(ssum, 32);
    float* red = ((float*)smem) + 16;
    if (lane == 0) red[wave] = ssum;
    __syncthreads();
    if (tid == 0) {
      float tot = 0.0f;
      for (int w = 0; w < 8; w++) tot += red[w];
      out[0] = -tot / (float)NROWS;
    }
  }
}

extern "C" void kernel_launch(void* const* d_in, const int* in_sizes, int n_in,
                              void* d_out, int out_size, void* d_ws, size_t ws_size,
                              hipStream_t stream) {
  const float* X = (const float*)d_in[0];
  float* out = (float*)d_out;
  char* ws = (char*)d_ws;
  unsigned int* Xn8 = (unsigned int*)ws;
  float* density = (float*)(ws + (size_t)NROWS * KDIM);
  unsigned int* ticket = (unsigned int*)(density + NROWS);

  hipFuncSetAttribute((const void*)kde_gemm,
                      hipFuncAttributeMaxDynamicSharedMemorySize, 65536);

  kde_normalize<<<NROWS / 4, 256, 0, stream>>>(X, Xn8, density, ticket);
  kde_gemm<<<dim3(NT, NSTRIP), 512, 65536, stream>>>((const unsigned char*)ws,
                                                     density, ticket, out);
}